// Round 10
// baseline (139.243 us; speedup 1.0000x reference)
//
#include <hip/hip_runtime.h>
#include <math.h>

// LinearAttention1d: b=8, dim=64, t=16384, heads=4, dim_head=32, inner=128
//
// Collapsed math (exp-safe without max subtraction: q_raw,k_raw ~ N(0,1)):
//   Zq[b,c]   = sum_t exp(q_raw[c,t])
//   ksum[b,c] = sum_t exp(k_raw[c,t]) / Zt[b,h,t]   (softmax over d=32 per t)
//   vsum[b,c] = Wv[c,:] . xsum[b,:]
//   y[b,o,t]  = sum_c wout[o,c]*ksum*vsum/Zq * exp(q_raw[c,t]) + b_out[o]
//
// R10 = R7's proven envelope (10 KB atomic ws, 2 compute kernels, no pbuf)
// with TBK 256->128: 1024 blocks/kernel, k1 LDS 18.4 KB (8 blocks/CU),
// k2 LDS 28 KB (5 blocks/CU) — ~2x resident waves for latency hiding.
// MFMA 16x16x32 bf16 layouts (verified): A[m=lane&15][k=quad*8+j],
//   B[k=quad*8+j][n=lane&15], C col=lane&15, row=quad*4+reg.

typedef short short8 __attribute__((ext_vector_type(8)));
typedef short short4s __attribute__((ext_vector_type(4)));
typedef float f32x4 __attribute__((ext_vector_type(4)));

namespace {
constexpr int NB = 8;
constexpr int NC = 64;           // in/out channels
constexpr int NT = 16384;
constexpr int NI = 128;          // inner = heads*dim_head
constexpr int TBK = 128;         // timesteps per block (both kernels)
constexpr int CPB = NT / TBK;    // 128 chunks per batch
constexpr int NBLK = NB * CPB;   // 1024 blocks
constexpr int XSP = 72;          // xs[t][c] bf16 row stride
constexpr int PTP = 136;         // pt[t][c] bf16 row stride
constexpr int PT  = 32;          // p-transpose subtile timesteps

// ws float offsets — atomic totals (zeroed each launch): 2560 floats = 10 KB
constexpr int WS_ZQ   = 0;                     // [NB][NI]
constexpr int WS_KSUM = WS_ZQ + NB * NI;       // [NB][NI]
constexpr int WS_XSUM = WS_KSUM + NB * NI;     // [NB][NC]
constexpr int WS_NFLOAT = WS_XSUM + NB * NC;   // 2560
}

__device__ __forceinline__ unsigned short f2bf(float f) {
  unsigned u = __float_as_uint(f);
  u += 0x7fffu + ((u >> 16) & 1u);   // RNE
  return (unsigned short)(u >> 16);
}

// stage 128-t x strip (fp32, coalesced float4) -> bf16 xs[t][c]
template <bool XS>
__device__ __forceinline__ void stage_x(const float* __restrict__ xb, int t0,
                                        unsigned short* xs, float* xsum_dst, int tid) {
  const int c = tid >> 2, tq = tid & 3;
  const float4* xr = (const float4*)(xb + (size_t)c * NT + t0);
  float s = 0.f;
#pragma unroll 4
  for (int i = 0; i < 8; ++i) {
    const int tv = tq + 4 * i;          // float4 index 0..31
    float4 v = xr[tv];
    if (XS) s += (v.x + v.y) + (v.z + v.w);
    const int t = 4 * tv;
    xs[(t + 0) * XSP + c] = f2bf(v.x);
    xs[(t + 1) * XSP + c] = f2bf(v.y);
    xs[(t + 2) * XSP + c] = f2bf(v.z);
    xs[(t + 3) * XSP + c] = f2bf(v.w);
  }
  if (XS) {
    s += __shfl_xor(s, 1, 64);
    s += __shfl_xor(s, 2, 64);
    if (tq == 0) atomicAdd(xsum_dst + c, s);
  }
}

// Wq A-frags for rows 32w..32w+31 (2 row-tiles x 2 K-steps)
__device__ __forceinline__ void load_aq(const float* __restrict__ wqkv, int w,
                                        int lm, int quad, short8 aq[2][2]) {
#pragma unroll
  for (int tile = 0; tile < 2; ++tile)
#pragma unroll
    for (int s = 0; s < 2; ++s) {
      const float* pq = wqkv + (size_t)(32 * w + tile * 16 + lm) * NC + s * 32 + quad * 8;
#pragma unroll
      for (int j = 0; j < 8; ++j) aq[tile][s][j] = (short)f2bf(pq[j]);
    }
}

// ---------------------------------------------------------------------------
// k1: stats. 1024 blocks, 18.4 KB LDS, wave = head.
// ---------------------------------------------------------------------------
__global__ __launch_bounds__(256) void la_stats(
    const float* __restrict__ x, const float* __restrict__ wqkv,
    float* __restrict__ ws)
{
  __shared__ __align__(16) unsigned short xs[TBK * XSP];  // 18,432 B

  const int bid = blockIdx.x;
  const int b = bid >> 7, chunk = bid & 127;
  const int tid = threadIdx.x, lane = tid & 63;
  const int w = __builtin_amdgcn_readfirstlane(tid >> 6);
  const int lm = lane & 15, quad = lane >> 4;
  const float* xb = x + (size_t)b * NC * NT;

  stage_x<true>(xb, chunk * TBK, xs, ws + WS_XSUM + b * NC, tid);

  short8 aq[2][2], ak[2][2];
  load_aq(wqkv, w, lm, quad, aq);
#pragma unroll
  for (int tile = 0; tile < 2; ++tile)
#pragma unroll
    for (int s = 0; s < 2; ++s) {
      const float* pk = wqkv + (size_t)(NI + 32 * w + tile * 16 + lm) * NC + s * 32 + quad * 8;
#pragma unroll
      for (int j = 0; j < 8; ++j) ak[tile][s][j] = (short)f2bf(pk[j]);
    }

  float zq_acc[2][4] = {};
  float ks_acc[2][4] = {};
  __syncthreads();

  for (int tc = 0; tc < TBK / 16; ++tc) {   // 8 t-tiles
    short8 bf[2];
#pragma unroll
    for (int s = 0; s < 2; ++s)
      bf[s] = *(const short8*)&xs[(tc * 16 + lm) * XSP + s * 32 + quad * 8];
    f32x4 cq[2] = {{0,0,0,0},{0,0,0,0}}, ck[2] = {{0,0,0,0},{0,0,0,0}};
#pragma unroll
    for (int tile = 0; tile < 2; ++tile)
#pragma unroll
      for (int s = 0; s < 2; ++s) {
        cq[tile] = __builtin_amdgcn_mfma_f32_16x16x32_bf16(aq[tile][s], bf[s], cq[tile], 0, 0, 0);
        ck[tile] = __builtin_amdgcn_mfma_f32_16x16x32_bf16(ak[tile][s], bf[s], ck[tile], 0, 0, 0);
      }
    float ke[2][4];
    float zt = 0.f;
#pragma unroll
    for (int tile = 0; tile < 2; ++tile)
#pragma unroll
      for (int r = 0; r < 4; ++r) {
        zq_acc[tile][r] += __expf(cq[tile][r]);
        float e = __expf(ck[tile][r]);
        ke[tile][r] = e;
        zt += e;
      }
    zt += __shfl_xor(zt, 16, 64);   // k rows live across quads; col fixed
    zt += __shfl_xor(zt, 32, 64);
    const float rz = __builtin_amdgcn_rcpf(zt);
#pragma unroll
    for (int tile = 0; tile < 2; ++tile)
#pragma unroll
      for (int r = 0; r < 4; ++r)
        ks_acc[tile][r] = fmaf(ke[tile][r], rz, ks_acc[tile][r]);
  }

  // reduce over 16 cols, one atomic per channel from lm==0 lanes
#pragma unroll
  for (int tile = 0; tile < 2; ++tile)
#pragma unroll
    for (int r = 0; r < 4; ++r) {
      float a = zq_acc[tile][r], k = ks_acc[tile][r];
#pragma unroll
      for (int off = 1; off < 16; off <<= 1) {
        a += __shfl_xor(a, off, 64);
        k += __shfl_xor(k, off, 64);
      }
      if (lm == 0) {
        const int c = 32 * w + tile * 16 + quad * 4 + r;
        atomicAdd(ws + WS_ZQ + b * NI + c, a);
        atomicAdd(ws + WS_KSUM + b * NI + c, k);
      }
    }
}

// ---------------------------------------------------------------------------
// k2: prologue reads totals -> Weff; recompute q -> exp -> transpose -> y.
// 1024 blocks, 28 KB LDS.
// ---------------------------------------------------------------------------
__global__ __launch_bounds__(256) void la_out(
    const float* __restrict__ x, const float* __restrict__ wqkv,
    const float* __restrict__ wout, const float* __restrict__ bout,
    const float* __restrict__ ws, float* __restrict__ y)
{
  __shared__ __align__(16) unsigned short xs[TBK * XSP];  // 18,432 B
  __shared__ __align__(16) unsigned short pt[PT * PTP];   //  8,704 B
  __shared__ float scale_s[NI];
  __shared__ float xsum_s[NC];

  const int bid = blockIdx.x;
  const int b = bid >> 7, chunk = bid & 127;
  const int tid = threadIdx.x, lane = tid & 63;
  const int w = __builtin_amdgcn_readfirstlane(tid >> 6);
  const int lm = lane & 15, quad = lane >> 4;
  const int t0 = chunk * TBK;
  const float* xb = x + (size_t)b * NC * NT;

  stage_x<false>(xb, t0, xs, nullptr, tid);

  // ---- prologue: totals -> scale_s (tiny, L2-resident; R7-proven) ----
  if (tid < NC) xsum_s[tid] = ws[WS_XSUM + b * NC + tid];
  __syncthreads();
  if (tid < NI) {
    float vs = 0.f;
    const float* wv = wqkv + (size_t)(2 * NI + tid) * NC;
#pragma unroll 8
    for (int cc = 0; cc < NC; ++cc) vs = fmaf(wv[cc], xsum_s[cc], vs);
    scale_s[tid] = ws[WS_KSUM + b * NI + tid] * vs / ws[WS_ZQ + b * NI + tid];
  }
  __syncthreads();

  // ---- A-frags: Wq rows 32w.. ; Weff rows 16w.. (K=128) ; bias ----
  short8 aq[2][2];
  load_aq(wqkv, w, lm, quad, aq);
  short8 aw[4];
  {
    const int o = 16 * w + lm;
#pragma unroll
    for (int s = 0; s < 4; ++s) {
      const float* wo = wout + (size_t)o * NI + s * 32 + quad * 8;
#pragma unroll
      for (int j = 0; j < 8; ++j)
        aw[s][j] = (short)f2bf(wo[j] * scale_s[s * 32 + quad * 8 + j]);
    }
  }
  float bias[4];
#pragma unroll
  for (int r = 0; r < 4; ++r) bias[r] = bout[16 * w + quad * 4 + r];

  // ---- main loop: 4 subtiles of 32 t: p = exp(q GEMM) -> pt -> y GEMM ----
  for (int sub = 0; sub < TBK / PT; ++sub) {
    for (int tc = 0; tc < PT / 16; ++tc) {
      const int tl = sub * PT + tc * 16;
      short8 bf[2];
#pragma unroll
      for (int s = 0; s < 2; ++s)
        bf[s] = *(const short8*)&xs[(tl + lm) * XSP + s * 32 + quad * 8];
      f32x4 cq[2] = {{0,0,0,0},{0,0,0,0}};
#pragma unroll
      for (int tile = 0; tile < 2; ++tile)
#pragma unroll
        for (int s = 0; s < 2; ++s)
          cq[tile] = __builtin_amdgcn_mfma_f32_16x16x32_bf16(aq[tile][s], bf[s], cq[tile], 0, 0, 0);
#pragma unroll
      for (int tile = 0; tile < 2; ++tile) {
        short4s pv;
#pragma unroll
        for (int r = 0; r < 4; ++r) pv[r] = (short)f2bf(__expf(cq[tile][r]));
        *(short4s*)&pt[(tc * 16 + lm) * PTP + 32 * w + tile * 16 + quad * 4] = pv;
      }
    }
    __syncthreads();
    for (int tc = 0; tc < PT / 16; ++tc) {
      short8 bp[4];
#pragma unroll
      for (int s = 0; s < 4; ++s)
        bp[s] = *(const short8*)&pt[(tc * 16 + lm) * PTP + s * 32 + quad * 8];
      f32x4 acc = {bias[0], bias[1], bias[2], bias[3]};
#pragma unroll
      for (int s = 0; s < 4; ++s)
        acc = __builtin_amdgcn_mfma_f32_16x16x32_bf16(aw[s], bp[s], acc, 0, 0, 0);
#pragma unroll
      for (int r = 0; r < 4; ++r)
        y[((size_t)b * NC + 16 * w + quad * 4 + r) * NT + t0 + sub * PT + tc * 16 + lm] = acc[r];
    }
    __syncthreads();
  }
}

// ---------------------------------------------------------------------------
extern "C" void kernel_launch(void* const* d_in, const int* in_sizes, int n_in,
                              void* d_out, int out_size, void* d_ws, size_t ws_size,
                              hipStream_t stream)
{
  const float* x    = (const float*)d_in[0];
  const float* wqkv = (const float*)d_in[1];
  const float* wout = (const float*)d_in[2];
  const float* bout = (const float*)d_in[3];
  float* y  = (float*)d_out;
  float* ws = (float*)d_ws;

  // Guard: convert any workspace shortfall into a clean absmax failure.
  if (ws_size < (size_t)WS_NFLOAT * sizeof(float)) return;

  hipMemsetAsync(ws, 0, (size_t)WS_NFLOAT * sizeof(float), stream);
  la_stats<<<dim3(NBLK), 256, 0, stream>>>(x, wqkv, ws);
  la_out<<<dim3(NBLK), 256, 0, stream>>>(x, wqkv, wout, bout, ws, y);
}

// Round 11
// 114.065 us; speedup vs baseline: 1.2207x; 1.2207x over previous
//
#include <hip/hip_runtime.h>
#include <math.h>

// LinearAttention1d: b=8, dim=64, t=16384, heads=4, dim_head=32, inner=128
//
// Collapsed math (exp-safe without max subtraction: q_raw,k_raw ~ N(0,1)):
//   Zq[b,c]   = sum_t exp(q_raw[c,t])
//   ksum[b,c] = sum_t exp(k_raw[c,t]) / Zt[b,h,t]   (softmax over d=32 per t)
//   vsum[b,c] = Wv[c,:] . xsum[b,:]
//   y[b,o,t]  = sum_c wout[o,c]*ksum*vsum/Zq * exp(q_raw[c,t]) + b_out[o]
//
// R11 = R7 (proven: TBK=256, 512 blocks, 10KB atomic totals) with ONE change:
// 8x replicated accumulator banks (80 KB, rep = chunk&7) to spread atomic
// RMW serialization across 8x more L2 cachelines. R10 PMC showed la_stats
// at 44 us with all pipes <16% busy and 4.3 MB of atomic writeback traffic
// -> per-line atomic serialization is the prime stall suspect.
// MFMA 16x16x32 bf16 layouts (verified): A[m=lane&15][k=quad*8+j],
//   B[k=quad*8+j][n=lane&15], C col=lane&15, row=quad*4+reg.

typedef short short8 __attribute__((ext_vector_type(8)));
typedef short short4s __attribute__((ext_vector_type(4)));
typedef float f32x4 __attribute__((ext_vector_type(4)));

namespace {
constexpr int NB = 8;
constexpr int NC = 64;           // in/out channels
constexpr int NT = 16384;
constexpr int NI = 128;          // inner = heads*dim_head
constexpr int TBK = 256;         // timesteps per block
constexpr int CPB = NT / TBK;    // 64 chunks per batch
constexpr int NBLK = NB * CPB;   // 512 blocks
constexpr int XSP = 72;          // xs[t][c] bf16 row stride
constexpr int PTP = 136;         // pt[t][c] bf16 row stride
constexpr int PT  = 32;          // p-transpose subtile timesteps
constexpr int REP = 8;           // accumulator replication factor

// ws float offsets — replicated atomic totals (zeroed each launch): 80 KB
constexpr int WS_ZQ   = 0;                           // [REP][NB][NI]
constexpr int WS_KSUM = WS_ZQ + REP * NB * NI;       // [REP][NB][NI]
constexpr int WS_XSUM = WS_KSUM + REP * NB * NI;     // [REP][NB][NC]
constexpr int WS_NFLOAT = WS_XSUM + REP * NB * NC;   // 20480 floats = 80 KB
}

__device__ __forceinline__ unsigned short f2bf(float f) {
  unsigned u = __float_as_uint(f);
  u += 0x7fffu + ((u >> 16) & 1u);   // RNE
  return (unsigned short)(u >> 16);
}

// stage x strip (fp32, coalesced float4) -> bf16 xs[t][c]; optional xsum atomic
template <bool XS>
__device__ __forceinline__ void stage_x(const float* __restrict__ xb, int t0,
                                        unsigned short* xs, float* xsum_dst, int tid) {
  const int c = tid >> 2, tq = tid & 3;
  const float4* xr = (const float4*)(xb + (size_t)c * NT + t0);
  float s = 0.f;
#pragma unroll 4
  for (int i = 0; i < 16; ++i) {
    const int tv = tq + 4 * i;
    float4 v = xr[tv];
    if (XS) s += (v.x + v.y) + (v.z + v.w);
    const int t = 4 * tv;
    xs[(t + 0) * XSP + c] = f2bf(v.x);
    xs[(t + 1) * XSP + c] = f2bf(v.y);
    xs[(t + 2) * XSP + c] = f2bf(v.z);
    xs[(t + 3) * XSP + c] = f2bf(v.w);
  }
  if (XS) {
    s += __shfl_xor(s, 1, 64);
    s += __shfl_xor(s, 2, 64);
    if (tq == 0) atomicAdd(xsum_dst + c, s);
  }
}

// load Wq A-frags for rows 32w..32w+31 (2 row-tiles x 2 K-steps)
__device__ __forceinline__ void load_aq(const float* __restrict__ wqkv, int w,
                                        int lm, int quad, short8 aq[2][2]) {
#pragma unroll
  for (int tile = 0; tile < 2; ++tile)
#pragma unroll
    for (int s = 0; s < 2; ++s) {
      const float* pq = wqkv + (size_t)(32 * w + tile * 16 + lm) * NC + s * 32 + quad * 8;
#pragma unroll
      for (int j = 0; j < 8; ++j) aq[tile][s][j] = (short)f2bf(pq[j]);
    }
}

// ---------------------------------------------------------------------------
// k1: stats. 512 blocks, wave = head.
// ---------------------------------------------------------------------------
__global__ __launch_bounds__(256) void la_stats(
    const float* __restrict__ x, const float* __restrict__ wqkv,
    float* __restrict__ ws)
{
  __shared__ __align__(16) unsigned short xs[TBK * XSP];  // 36,864 B

  const int bid = blockIdx.x;
  const int b = bid >> 6, chunk = bid & 63;
  const int rep = chunk & (REP - 1);
  const int tid = threadIdx.x, lane = tid & 63;
  const int w = __builtin_amdgcn_readfirstlane(tid >> 6);
  const int lm = lane & 15, quad = lane >> 4;
  const float* xb = x + (size_t)b * NC * NT;

  stage_x<true>(xb, chunk * TBK, xs, ws + WS_XSUM + (rep * NB + b) * NC, tid);

  short8 aq[2][2], ak[2][2];
  load_aq(wqkv, w, lm, quad, aq);
#pragma unroll
  for (int tile = 0; tile < 2; ++tile)
#pragma unroll
    for (int s = 0; s < 2; ++s) {
      const float* pk = wqkv + (size_t)(NI + 32 * w + tile * 16 + lm) * NC + s * 32 + quad * 8;
#pragma unroll
      for (int j = 0; j < 8; ++j) ak[tile][s][j] = (short)f2bf(pk[j]);
    }

  float zq_acc[2][4] = {};
  float ks_acc[2][4] = {};
  __syncthreads();

  for (int tc = 0; tc < TBK / 16; ++tc) {
    short8 bf[2];
#pragma unroll
    for (int s = 0; s < 2; ++s)
      bf[s] = *(const short8*)&xs[(tc * 16 + lm) * XSP + s * 32 + quad * 8];
    f32x4 cq[2] = {{0,0,0,0},{0,0,0,0}}, ck[2] = {{0,0,0,0},{0,0,0,0}};
#pragma unroll
    for (int tile = 0; tile < 2; ++tile)
#pragma unroll
      for (int s = 0; s < 2; ++s) {
        cq[tile] = __builtin_amdgcn_mfma_f32_16x16x32_bf16(aq[tile][s], bf[s], cq[tile], 0, 0, 0);
        ck[tile] = __builtin_amdgcn_mfma_f32_16x16x32_bf16(ak[tile][s], bf[s], ck[tile], 0, 0, 0);
      }
    float ke[2][4];
    float zt = 0.f;
#pragma unroll
    for (int tile = 0; tile < 2; ++tile)
#pragma unroll
      for (int r = 0; r < 4; ++r) {
        zq_acc[tile][r] += __expf(cq[tile][r]);
        float e = __expf(ck[tile][r]);
        ke[tile][r] = e;
        zt += e;
      }
    zt += __shfl_xor(zt, 16, 64);   // k rows live across quads; col fixed
    zt += __shfl_xor(zt, 32, 64);
    const float rz = __builtin_amdgcn_rcpf(zt);
#pragma unroll
    for (int tile = 0; tile < 2; ++tile)
#pragma unroll
      for (int r = 0; r < 4; ++r)
        ks_acc[tile][r] = fmaf(ke[tile][r], rz, ks_acc[tile][r]);
  }

  // reduce over 16 cols, one atomic per channel into this block's replica
#pragma unroll
  for (int tile = 0; tile < 2; ++tile)
#pragma unroll
    for (int r = 0; r < 4; ++r) {
      float a = zq_acc[tile][r], k = ks_acc[tile][r];
#pragma unroll
      for (int off = 1; off < 16; off <<= 1) {
        a += __shfl_xor(a, off, 64);
        k += __shfl_xor(k, off, 64);
      }
      if (lm == 0) {
        const int c = 32 * w + tile * 16 + quad * 4 + r;
        atomicAdd(ws + WS_ZQ + (rep * NB + b) * NI + c, a);
        atomicAdd(ws + WS_KSUM + (rep * NB + b) * NI + c, k);
      }
    }
}

// ---------------------------------------------------------------------------
// k2: prologue sums replicas -> Weff; recompute q -> exp -> transpose -> y.
// ---------------------------------------------------------------------------
__global__ __launch_bounds__(256) void la_out(
    const float* __restrict__ x, const float* __restrict__ wqkv,
    const float* __restrict__ wout, const float* __restrict__ bout,
    const float* __restrict__ ws, float* __restrict__ y)
{
  __shared__ __align__(16) unsigned short xs[TBK * XSP];  // 36,864 B
  __shared__ __align__(16) unsigned short pt[PT * PTP];   //  8,704 B
  __shared__ float scale_s[NI];
  __shared__ float xsum_s[NC];

  const int bid = blockIdx.x;
  const int b = bid >> 6, chunk = bid & 63;
  const int tid = threadIdx.x, lane = tid & 63;
  const int w = __builtin_amdgcn_readfirstlane(tid >> 6);
  const int lm = lane & 15, quad = lane >> 4;
  const int t0 = chunk * TBK;
  const float* xb = x + (size_t)b * NC * NT;

  stage_x<false>(xb, t0, xs, nullptr, tid);

  // ---- prologue: sum 8 replicas -> scale_s (tiny, L2-resident) ----
  if (tid < NC) {
    float s = 0.f;
#pragma unroll
    for (int rp = 0; rp < REP; ++rp) s += ws[WS_XSUM + (rp * NB + b) * NC + tid];
    xsum_s[tid] = s;
  }
  __syncthreads();
  if (tid < NI) {
    float vs = 0.f;
    const float* wv = wqkv + (size_t)(2 * NI + tid) * NC;
#pragma unroll 8
    for (int cc = 0; cc < NC; ++cc) vs = fmaf(wv[cc], xsum_s[cc], vs);
    float zq_t = 0.f, ks_t = 0.f;
#pragma unroll
    for (int rp = 0; rp < REP; ++rp) {
      zq_t += ws[WS_ZQ + (rp * NB + b) * NI + tid];
      ks_t += ws[WS_KSUM + (rp * NB + b) * NI + tid];
    }
    scale_s[tid] = ks_t * vs / zq_t;
  }
  __syncthreads();

  // ---- A-frags: Wq rows 32w.. ; Weff rows 16w.. (K=128) ; bias ----
  short8 aq[2][2];
  load_aq(wqkv, w, lm, quad, aq);
  short8 aw[4];
  {
    const int o = 16 * w + lm;
#pragma unroll
    for (int s = 0; s < 4; ++s) {
      const float* wo = wout + (size_t)o * NI + s * 32 + quad * 8;
#pragma unroll
      for (int j = 0; j < 8; ++j)
        aw[s][j] = (short)f2bf(wo[j] * scale_s[s * 32 + quad * 8 + j]);
    }
  }
  float bias[4];
#pragma unroll
  for (int r = 0; r < 4; ++r) bias[r] = bout[16 * w + quad * 4 + r];

  // ---- main loop: 32-t subtiles: p = exp(q GEMM) -> pt -> y GEMM ----
  for (int sub = 0; sub < TBK / PT; ++sub) {
    for (int tc = 0; tc < PT / 16; ++tc) {
      const int tl = sub * PT + tc * 16;
      short8 bf[2];
#pragma unroll
      for (int s = 0; s < 2; ++s)
        bf[s] = *(const short8*)&xs[(tl + lm) * XSP + s * 32 + quad * 8];
      f32x4 cq[2] = {{0,0,0,0},{0,0,0,0}};
#pragma unroll
      for (int tile = 0; tile < 2; ++tile)
#pragma unroll
        for (int s = 0; s < 2; ++s)
          cq[tile] = __builtin_amdgcn_mfma_f32_16x16x32_bf16(aq[tile][s], bf[s], cq[tile], 0, 0, 0);
#pragma unroll
      for (int tile = 0; tile < 2; ++tile) {
        short4s pv;
#pragma unroll
        for (int r = 0; r < 4; ++r) pv[r] = (short)f2bf(__expf(cq[tile][r]));
        *(short4s*)&pt[(tc * 16 + lm) * PTP + 32 * w + tile * 16 + quad * 4] = pv;
      }
    }
    __syncthreads();
    for (int tc = 0; tc < PT / 16; ++tc) {
      short8 bp[4];
#pragma unroll
      for (int s = 0; s < 4; ++s)
        bp[s] = *(const short8*)&pt[(tc * 16 + lm) * PTP + s * 32 + quad * 8];
      f32x4 acc = {bias[0], bias[1], bias[2], bias[3]};
#pragma unroll
      for (int s = 0; s < 4; ++s)
        acc = __builtin_amdgcn_mfma_f32_16x16x32_bf16(aw[s], bp[s], acc, 0, 0, 0);
#pragma unroll
      for (int r = 0; r < 4; ++r)
        y[((size_t)b * NC + 16 * w + quad * 4 + r) * NT + t0 + sub * PT + tc * 16 + lm] = acc[r];
    }
    __syncthreads();
  }
}

// ---------------------------------------------------------------------------
extern "C" void kernel_launch(void* const* d_in, const int* in_sizes, int n_in,
                              void* d_out, int out_size, void* d_ws, size_t ws_size,
                              hipStream_t stream)
{
  const float* x    = (const float*)d_in[0];
  const float* wqkv = (const float*)d_in[1];
  const float* wout = (const float*)d_in[2];
  const float* bout = (const float*)d_in[3];
  float* y  = (float*)d_out;
  float* ws = (float*)d_ws;

  // Guard: convert any workspace shortfall into a clean absmax failure.
  if (ws_size < (size_t)WS_NFLOAT * sizeof(float)) return;

  hipMemsetAsync(ws, 0, (size_t)WS_NFLOAT * sizeof(float), stream);
  la_stats<<<dim3(NBLK), 256, 0, stream>>>(x, wqkv, ws);
  la_out<<<dim3(NBLK), 256, 0, stream>>>(x, wqkv, wout, bout, ws, y);
}